// Round 8
// baseline (1434.455 us; speedup 1.0000x reference)
//
#include <hip/hip_runtime.h>
#include <hip/hip_bf16.h>

typedef _Float16 half8  __attribute__((ext_vector_type(8)));
typedef _Float16 half4_t __attribute__((ext_vector_type(4)));
typedef float    floatx4 __attribute__((ext_vector_type(4)));
typedef int      intx4   __attribute__((ext_vector_type(4)));

#define B_DIM   16384
#define IN_D    2048
#define HV_D    8192
#define NC      1000
#define NCP     1024
#define SCORES_N (B_DIM * NC)

// async global->LDS, 16B per lane; LDS side is wave-uniform base + lane*16
#define GLD16(gp, lp) __builtin_amdgcn_global_load_lds( \
    (const __attribute__((address_space(1))) void*)(gp), \
    (__attribute__((address_space(3))) void*)(lp), 16, 0, 0)

// ---------- P1: x (fp32) -> x_h (fp16 round-nearest). Single-precision path ----------
__global__ void k_split(const float* __restrict__ x, _Float16* __restrict__ xh) {
    size_t i = (size_t)blockIdx.x * 256 + threadIdx.x;
    floatx4 v = ((const floatx4*)x)[i];
    half4_t h;
#pragma unroll
    for (int j = 0; j < 4; ++j) h[j] = (_Float16)v[j];
    ((half4_t*)xh)[i] = h;
}

// ---------- P2: proj [K=2048][N=8192] fp32 -> projT [N][K] fp16 (LDS-tiled) ----------
__global__ void k_transpose_proj(const float* __restrict__ p, _Float16* __restrict__ pT) {
    __shared__ float tile[64][65];
    const int t = threadIdx.x;
    const int nt = blockIdx.x * 64;
    const int kt = blockIdx.y * 64;
    const int tr = t >> 4, tc = (t & 15) * 4;
#pragma unroll
    for (int s = 0; s < 4; ++s) {
        int r = tr + s * 16;
        floatx4 v = *(const floatx4*)&p[(size_t)(kt + r) * HV_D + nt + tc];
        tile[r][tc] = v[0]; tile[r][tc + 1] = v[1];
        tile[r][tc + 2] = v[2]; tile[r][tc + 3] = v[3];
    }
    __syncthreads();
#pragma unroll
    for (int s = 0; s < 4; ++s) {
        int rn = tr + s * 16;
        half4_t o;
#pragma unroll
        for (int j = 0; j < 4; ++j) o[j] = (_Float16)tile[tc + j][rn];
        *(half4_t*)&pT[(size_t)(nt + rn) * IN_D + kt + tc] = o;
    }
}

// ---------- P3: class_hv [8192][1000] fp32 -> classT [1024][8192] i8 ----------
__global__ void k_pack_class(const float* __restrict__ c, signed char* __restrict__ cT) {
    __shared__ signed char tile[64][68];
    const int t = threadIdx.x;
    const int nt = blockIdx.x * 64;
    const int kt = blockIdx.y * 64;
    const int nl = t & 63;
    const int n = nt + nl;
#pragma unroll
    for (int s = 0; s < 16; ++s) {
        const int kl = s * 4 + (t >> 6);
        signed char v = 0;
        if (n < NC) {
            float f = c[(size_t)(kt + kl) * NC + n];
            v = (f >= 0.f) ? (signed char)1 : (signed char)-1;
        }
        tile[kl][nl] = v;
    }
    __syncthreads();
    const int wn = t >> 2;
    const int wk = (t & 3) * 16;
    intx4 o;
    signed char* ob = (signed char*)&o;
#pragma unroll
    for (int j = 0; j < 16; ++j) ob[j] = tile[wk + j][wn];
    *(intx4*)&cT[(size_t)(nt + wn) * HV_D + kt + wk] = o;
}

// ---------- G1: hv = x@proj, fp16, 256x256 8-PHASE counted-vmcnt (m201-template port) ----------
// BM=BN=256, BK=64, 8 waves (2M x 4N), wave tile 128x64, LDS 2x(32+32)=128KB dbuf,
// 1 block/CU. Per iter (2 K-tiles): 8 phases of {ds-reads || 1 half-tile stage (2 GLD16)
// -> sched_barrier+s_barrier -> setprio(1) 16 MFMA setprio(0) -> [vmcnt(6) @ p4,p8]
// -> barrier}. Stage slots are WAR-safe (each targets a region whose last reader closed
// >=1 barrier before): p1:A?1(t+1->b1) p2:B?0(t+2->b0) p3:B?1(t+2) p4:A?0(t+2)
// p5:A?1(t+2) p6:B?0(t+3->b1) p7:B?1(t+3) p8:A?0(t+3). Ledger: 14 outstanding at
// p4/p8, vmcnt(6) forces exactly the next half-tile set -- never 0 in loop.
// Reads per phase: 12/4/8/0 (A-quad re-read, B-sets held in regs). Per-element
// accumulation order (ks0,ks1 per K-tile, K-tiles ascending) == R7, absmax unchanged.
__launch_bounds__(512, 1)
__global__ void k_gemm1(const _Float16* __restrict__ xh,
                        const _Float16* __restrict__ pT,
                        float* __restrict__ hv_out, signed char* __restrict__ hvb) {
    __shared__ _Float16 sA[2][256 * 64];   // 2 x 32 KB
    __shared__ _Float16 sB[2][256 * 64];   // 2 x 32 KB
    const int t = threadIdx.x;
    const int w = t >> 6, l = t & 63;
    const int m0 = blockIdx.y * 256, n0 = blockIdx.x * 256;
    const int wm = (w >> 2) * 128, wn = (w & 3) * 64;
    const int lm = l & 15, kq = l >> 4;
    const int srow  = t >> 3;                          // 0..63 (row within 64-row round)
    const int gcol  = ((t & 7) ^ ((t >> 3) & 7)) * 8;  // swizzled source chunk (f16 units)
    const int sbyte = t * 16;                          // linear LDS byte within 8KB round
    const int csw0  = (kq ^ (lm & 7)) * 8;             // read slots (proven pair: row&7==lm&7)
    const int csw1  = ((kq + 4) ^ (lm & 7)) * 8;

    floatx4 acc[8][4] = {};
    half8 A[4][2], B0[2][2], B1[2][2];

#define STAGE_A(d, h, kt) do { \
    GLD16(xh + (size_t)(m0 + (h) * 128 + srow) * IN_D + (kt) * 64 + gcol, \
          (char*)&sA[d][0] + (h) * 16384 + sbyte); \
    GLD16(xh + (size_t)(m0 + (h) * 128 + 64 + srow) * IN_D + (kt) * 64 + gcol, \
          (char*)&sA[d][0] + (h) * 16384 + 8192 + sbyte); \
} while (0)

#define STAGE_B(d, h, kt) do { \
    GLD16(pT + (size_t)(n0 + (h) * 128 + srow) * IN_D + (kt) * 64 + gcol, \
          (char*)&sB[d][0] + (h) * 16384 + sbyte); \
    GLD16(pT + (size_t)(n0 + (h) * 128 + 64 + srow) * IN_D + (kt) * 64 + gcol, \
          (char*)&sB[d][0] + (h) * 16384 + 8192 + sbyte); \
} while (0)

#define RD_A(d, mh) do { _Pragma("unroll") \
    for (int q = 0; q < 4; ++q) { \
        const int r_ = (wm + ((mh) * 4 + q) * 16 + lm) * 64; \
        A[q][0] = *(const half8*)&sA[d][r_ + csw0]; \
        A[q][1] = *(const half8*)&sA[d][r_ + csw1]; } } while (0)

#define RD_B(dst, d, nh) do { _Pragma("unroll") \
    for (int j = 0; j < 2; ++j) { \
        const int r_ = (wn + ((nh) * 2 + j) * 16 + lm) * 64; \
        dst[j][0] = *(const half8*)&sB[d][r_ + csw0]; \
        dst[j][1] = *(const half8*)&sB[d][r_ + csw1]; } } while (0)

#define MMQ(Bs, mh, nh) do { _Pragma("unroll") \
    for (int q = 0; q < 4; ++q) { _Pragma("unroll") \
      for (int j = 0; j < 2; ++j) { \
        acc[(mh)*4+q][(nh)*2+j] = __builtin_amdgcn_mfma_f32_16x16x32_f16(A[q][0], Bs[j][0], acc[(mh)*4+q][(nh)*2+j], 0, 0, 0); \
        acc[(mh)*4+q][(nh)*2+j] = __builtin_amdgcn_mfma_f32_16x16x32_f16(A[q][1], Bs[j][1], acc[(mh)*4+q][(nh)*2+j], 0, 0, 0); } } } while (0)

#define VM6 asm volatile("s_waitcnt vmcnt(6)" ::: "memory")
#define NOWAIT do {} while (0)

#define PH(RDS, STG, MFMAS, WAIT) do { \
    RDS; STG; \
    __builtin_amdgcn_sched_barrier(0); \
    __builtin_amdgcn_s_barrier(); \
    __builtin_amdgcn_sched_barrier(0); \
    __builtin_amdgcn_s_setprio(1); \
    MFMAS; \
    __builtin_amdgcn_s_setprio(0); \
    WAIT; \
    __builtin_amdgcn_sched_barrier(0); \
    __builtin_amdgcn_s_barrier(); \
    __builtin_amdgcn_sched_barrier(0); \
} while (0)

    // ---- prologue: t0 full + t1's B?0,B?1,A?0 (A?1 comes at iter0-p1); 14 loads out,
    // vmcnt(6) forces t0's 8 ----
    STAGE_B(0, 0, 0); STAGE_B(0, 1, 0); STAGE_A(0, 0, 0); STAGE_A(0, 1, 0);
    STAGE_B(1, 0, 1); STAGE_B(1, 1, 1); STAGE_A(1, 0, 1);
    VM6;
    __builtin_amdgcn_sched_barrier(0);
    __builtin_amdgcn_s_barrier();
    __builtin_amdgcn_sched_barrier(0);

#pragma unroll 1
    for (int i = 0; i < 16; ++i) {
        const int t1 = 2 * i + 1;
        const int t2 = (2 * i + 2 < 32) ? 2 * i + 2 : 31;  // clamped tail: garbage-but-safe
        const int t3 = (2 * i + 3 < 32) ? 2 * i + 3 : 31;
        // even tile (buf0)
        PH({ RD_A(0, 0); RD_B(B0, 0, 0); }, STAGE_A(1, 1, t1), MMQ(B0, 0, 0), NOWAIT);
        PH(RD_B(B1, 0, 1),                  STAGE_B(0, 0, t2), MMQ(B1, 0, 1), NOWAIT);
        PH(RD_A(0, 1),                      STAGE_B(0, 1, t2), MMQ(B0, 1, 0), NOWAIT);
        PH(NOWAIT,                          STAGE_A(0, 0, t2), MMQ(B1, 1, 1), VM6);
        // odd tile (buf1)
        PH({ RD_A(1, 0); RD_B(B0, 1, 0); }, STAGE_A(0, 1, t2), MMQ(B0, 0, 0), NOWAIT);
        PH(RD_B(B1, 1, 1),                  STAGE_B(1, 0, t3), MMQ(B1, 0, 1), NOWAIT);
        PH(RD_A(1, 1),                      STAGE_B(1, 1, t3), MMQ(B0, 1, 0), NOWAIT);
        PH(NOWAIT,                          STAGE_A(1, 0, t3), MMQ(B1, 1, 1), VM6);
    }
    asm volatile("s_waitcnt vmcnt(0)" ::: "memory");   // drain stray tail stages

    // ---- epilogue: C/D layout col=lane&15, row=(lane>>4)*4+reg (plain stores) ----
#pragma unroll
    for (int ms = 0; ms < 8; ++ms) {
#pragma unroll
        for (int ns = 0; ns < 4; ++ns) {
            const int m = m0 + wm + ms * 16 + kq * 4;
            const int n = n0 + wn + ns * 16 + lm;
#pragma unroll
            for (int r = 0; r < 4; ++r) {
                const int pos = (acc[ms][ns][r] >= 0.f);
                const size_t o = (size_t)(m + r) * HV_D + n;
                hv_out[o] = pos ? 1.f : -1.f;
                hvb[o] = (signed char)(pos ? 1 : -1);
            }
        }
    }
#undef PH
#undef VM6
#undef NOWAIT
#undef MMQ
#undef RD_A
#undef RD_B
#undef STAGE_A
#undef STAGE_B
}

// ---------- G2: scores = hv_bin @ class_hv, exact in i8 (K=8192) ----------
// R7 config verbatim: 64x256 block, BK=128, dbuf 80KB -> 2 blocks/CU, counted
// vmcnt(10) (never 0 in loop), peeled last tile.
__launch_bounds__(256, 2)
__global__ void k_gemm2(const signed char* __restrict__ hvb, const signed char* __restrict__ cT,
                        float* __restrict__ scores) {
    __shared__ signed char sA[2][64 * 128];    // 2 x  8 KB
    __shared__ signed char sB[2][256 * 128];   // 2 x 32 KB  => 80 KB total
    const int t = threadIdx.x;
    const int w = t >> 6, l = t & 63;

    const int orig = blockIdx.y * 4 + blockIdx.x;
    const int lid  = (orig & 7) * 128 + (orig >> 3);   // cpx = 1024/8 = 128
    const int bx = lid & 3, by = lid >> 2;

    const int m0 = by * 64, n0 = bx * 256;
    const int wm = (w >> 1) * 32, wn = (w & 1) * 128;  // wave tile 32x128
    const int lm = l & 15, kq = l >> 4;
    const int srow  = w * 8 + (l >> 3);                   // + i*32
    const int scol  = (((l & 7) ^ ((l >> 3) & 7))) * 16;  // swizzled source chunk (bytes)
    const int sbyte = w * 1024 + l * 16;                  // + i*4096

    intx4 acc[2][8] = {};

#define G2_STAGE(buf, kt) do { \
    const int k0_ = (kt) * 128; \
    _Pragma("unroll") \
    for (int i = 0; i < 2; ++i) \
        GLD16(hvb + (size_t)(m0 + srow + i * 32) * HV_D + k0_ + scol, \
              (char*)&sA[buf][0] + sbyte + i * 4096); \
    _Pragma("unroll") \
    for (int i = 0; i < 8; ++i) \
        GLD16(cT + (size_t)(n0 + srow + i * 32) * HV_D + k0_ + scol, \
              (char*)&sB[buf][0] + sbyte + i * 4096); \
} while (0)

#define G2_COMPUTE(buf) do { \
    _Pragma("unroll") \
    for (int ks = 0; ks < 2; ++ks) { \
        const int csw = ((ks * 4 + kq) ^ (lm & 7)) * 16; \
        intx4 b[8]; \
        _Pragma("unroll") \
        for (int ns = 0; ns < 8; ++ns) \
            b[ns] = *(const intx4*)&sB[buf][(wn + ns * 16 + lm) * 128 + csw]; \
        _Pragma("unroll") \
        for (int ms = 0; ms < 2; ++ms) { \
            intx4 a = *(const intx4*)&sA[buf][(wm + ms * 16 + lm) * 128 + csw]; \
            _Pragma("unroll") \
            for (int ns = 0; ns < 8; ++ns) \
                acc[ms][ns] = __builtin_amdgcn_mfma_i32_16x16x64_i8(a, b[ns], acc[ms][ns], 0, 0, 0); \
        } \
    } \
} while (0)

    // prologue: k-tile 0 into buf0
    G2_STAGE(0, 0);

#pragma unroll 1
    for (int kt = 0; kt < 63; ++kt) {
        const int cur = kt & 1;
        __builtin_amdgcn_s_barrier();              // WAR: all waves done with buf[cur^1]
        if (cur == 0) G2_STAGE(1, kt + 1); else G2_STAGE(0, kt + 1);
        asm volatile("s_waitcnt vmcnt(10)" ::: "memory");   // force buf[cur]'s 10 loads
        __builtin_amdgcn_sched_barrier(0);
        __builtin_amdgcn_s_barrier();              // RAW: cur's data visible to all
        __builtin_amdgcn_sched_barrier(0);
        if (cur == 0) G2_COMPUTE(0); else G2_COMPUTE(1);
    }
    // peeled last tile: kt=63, cur=1
    __builtin_amdgcn_s_barrier();
    asm volatile("s_waitcnt vmcnt(0)" ::: "memory");
    __builtin_amdgcn_sched_barrier(0);
    __builtin_amdgcn_s_barrier();
    __builtin_amdgcn_sched_barrier(0);
    G2_COMPUTE(1);

#undef G2_STAGE
#undef G2_COMPUTE

#pragma unroll
    for (int ms = 0; ms < 2; ++ms) {
#pragma unroll
        for (int ns = 0; ns < 8; ++ns) {
            const int m = m0 + wm + ms * 16 + kq * 4;
            const int n = n0 + wn + ns * 16 + lm;
            if (n < NC) {
#pragma unroll
                for (int r = 0; r < 4; ++r)
                    __builtin_nontemporal_store((float)acc[ms][ns][r],
                                                &scores[(size_t)(m + r) * NC + n]);
            }
        }
    }
}

extern "C" void kernel_launch(void* const* d_in, const int* in_sizes, int n_in,
                              void* d_out, int out_size, void* d_ws, size_t ws_size,
                              hipStream_t stream) {
    const float* x    = (const float*)d_in[0];   // [16384][2048]
    const float* proj = (const float*)d_in[1];   // [2048][8192]
    const float* chv  = (const float*)d_in[2];   // [8192][1000]
    float* out    = (float*)d_out;
    float* scores = out;                          // [16384][1000]
    float* hv_out = out + (size_t)SCORES_N;       // [16384][8192]

    // workspace layout (xl slot unused; offsets kept stable)
    char* ws = (char*)d_ws;
    _Float16*    xh  = (_Float16*)(ws);                         //  64 MiB
    _Float16*    pT  = (_Float16*)(ws + (size_t)134217728);     //  32 MiB
    signed char* cT  = (signed char*)(ws + (size_t)167772160);  //   8 MiB
    signed char* hvb = (signed char*)(ws + (size_t)176160768);  // 128 MiB

    k_split<<<(B_DIM * IN_D / 4) / 256, 256, 0, stream>>>(x, xh);
    k_transpose_proj<<<dim3(HV_D / 64, IN_D / 64), 256, 0, stream>>>(proj, pT);
    k_pack_class<<<dim3(NCP / 64, HV_D / 64), 256, 0, stream>>>(chv, cT);
    // single 256x256-tile gemm1 dispatch: 2048 blocks, 1 block/CU, 8 rounds
    k_gemm1<<<dim3(HV_D / 256, B_DIM / 256), 512, 0, stream>>>(xh, pT, hv_out, hvb);
    k_gemm2<<<dim3(NCP / 256, B_DIM / 64), 256, 0, stream>>>(hvb, cT, scores);
}